// Round 17
// baseline (73.064 us; speedup 1.0000x reference)
//
#include <hip/hip_runtime.h>
#include <math.h>

#define B 32
#define N 16384
#define DIM 64
#define HID 64
#define KD 16
#define DM 512
#define MP 16

#define GRID_SAL 1024   // 4 blocks/CU (r13: 2048 hurts)
#define ITERS 8         // 1024 * 8 * 64 rows = 524288 = B*N

typedef __attribute__((ext_vector_type(8))) _Float16 f16x8;
typedef __attribute__((ext_vector_type(2))) __fp16 fph2;   // cvt_pkrtz return type
typedef __attribute__((ext_vector_type(4))) float f32x4;

// tanh via exp + RAW v_rcp (no -ffast-math: '/' would emit the IEEE div sequence).
__device__ __forceinline__ float fast_tanh(float a) {
  const float e = __expf(2.f * a);
  return 1.f - 2.f * __builtin_amdgcn_rcpf(e + 1.f);
}

// ---------- Kernel 1: saliency (UNCHANGED from r16 — measured at HBM roofline ~20 us) ----------
__global__ __launch_bounds__(256) void k_saliency(
    const float* __restrict__ x, const float* __restrict__ W1,
    const float* __restrict__ b1, const float* __restrict__ w_s,
    float* __restrict__ sal) {
  const int t = threadIdx.x;
  const int lane = t & 63, wid = t >> 6;
  const int c16 = lane & 15, kq = lane >> 4;

  __shared__ __align__(16) _Float16 lWh[64 * 72];
  __shared__ __align__(16) _Float16 lWl[64 * 72];
  __shared__ __align__(16) float lws[64], lb1[64];
#pragma unroll
  for (int j = 0; j < 16; ++j) {
    const int i = t + 256 * j;
    const int k = i >> 6, col = i & 63;
    const float v = W1[i];
    const _Float16 h = (_Float16)v;
    lWh[col * 72 + k] = h;
    lWl[col * 72 + k] = (_Float16)(v - (float)h);
  }
  if (t < 64) { lws[t] = w_s[t]; lb1[t] = b1[t]; }
  __syncthreads();

  f16x8 WH[8], WL[8];
#pragma unroll
  for (int ct = 0; ct < 4; ++ct)
#pragma unroll
    for (int kc = 0; kc < 2; ++kc) {
      const int off = (ct * 16 + c16) * 72 + kc * 32 + kq * 8;
      WH[ct * 2 + kc] = *(const f16x8*)(lWh + off);
      WL[ct * 2 + kc] = *(const f16x8*)(lWl + off);
    }

#define PKSPLIT(va, vb, HW, LW) {                                                  \
    const fph2 h_ = __builtin_amdgcn_cvt_pkrtz((va), (vb));                        \
    const fph2 l_ = __builtin_amdgcn_cvt_pkrtz((va) - (float)h_[0],                \
                                               (vb) - (float)h_[1]);               \
    HW = __builtin_bit_cast(unsigned, h_);                                         \
    LW = __builtin_bit_cast(unsigned, l_); }

#define SAL_LOADS(b0, b1_, b2, b3, it_) {                                          \
    const size_t row_ = ((size_t)(it_) * GRID_SAL + blockIdx.x) * 64 + wid * 16 + c16; \
    const float* __restrict__ p_ = x + row_ * DIM + kq * 8;                        \
    b0 = *(const float4*)(p_);       b1_ = *(const float4*)(p_ + 4);               \
    b2 = *(const float4*)(p_ + 32);  b3 = *(const float4*)(p_ + 36); }

#define SAL_COMPUTE(b0, b1_, b2, b3, it_) {                                        \
    f32x4 a0 = (f32x4)0.f, a1 = (f32x4)0.f, a2 = (f32x4)0.f, a3 = (f32x4)0.f;      \
    { /* kc = 0 */                                                                 \
      uint4 H, L;                                                                  \
      PKSPLIT(b0.x, b0.y, H.x, L.x); PKSPLIT(b0.z, b0.w, H.y, L.y);                \
      PKSPLIT(b1_.x, b1_.y, H.z, L.z); PKSPLIT(b1_.z, b1_.w, H.w, L.w);            \
      const f16x8 bh = __builtin_bit_cast(f16x8, H);                               \
      const f16x8 bl = __builtin_bit_cast(f16x8, L);                               \
      a0 = __builtin_amdgcn_mfma_f32_16x16x32_f16(WH[0], bh, a0, 0, 0, 0);         \
      a1 = __builtin_amdgcn_mfma_f32_16x16x32_f16(WH[2], bh, a1, 0, 0, 0);         \
      a2 = __builtin_amdgcn_mfma_f32_16x16x32_f16(WH[4], bh, a2, 0, 0, 0);         \
      a3 = __builtin_amdgcn_mfma_f32_16x16x32_f16(WH[6], bh, a3, 0, 0, 0);         \
      a0 = __builtin_amdgcn_mfma_f32_16x16x32_f16(WL[0], bh, a0, 0, 0, 0);         \
      a1 = __builtin_amdgcn_mfma_f32_16x16x32_f16(WL[2], bh, a1, 0, 0, 0);         \
      a2 = __builtin_amdgcn_mfma_f32_16x16x32_f16(WL[4], bh, a2, 0, 0, 0);         \
      a3 = __builtin_amdgcn_mfma_f32_16x16x32_f16(WL[6], bh, a3, 0, 0, 0);         \
      a0 = __builtin_amdgcn_mfma_f32_16x16x32_f16(WH[0], bl, a0, 0, 0, 0);         \
      a1 = __builtin_amdgcn_mfma_f32_16x16x32_f16(WH[2], bl, a1, 0, 0, 0);         \
      a2 = __builtin_amdgcn_mfma_f32_16x16x32_f16(WH[4], bl, a2, 0, 0, 0);         \
      a3 = __builtin_amdgcn_mfma_f32_16x16x32_f16(WH[6], bl, a3, 0, 0, 0);         \
    }                                                                              \
    { /* kc = 1 */                                                                 \
      uint4 H, L;                                                                  \
      PKSPLIT(b2.x, b2.y, H.x, L.x); PKSPLIT(b2.z, b2.w, H.y, L.y);                \
      PKSPLIT(b3.x, b3.y, H.z, L.z); PKSPLIT(b3.z, b3.w, H.w, L.w);                \
      const f16x8 bh = __builtin_bit_cast(f16x8, H);                               \
      const f16x8 bl = __builtin_bit_cast(f16x8, L);                               \
      a0 = __builtin_amdgcn_mfma_f32_16x16x32_f16(WH[1], bh, a0, 0, 0, 0);         \
      a1 = __builtin_amdgcn_mfma_f32_16x16x32_f16(WH[3], bh, a1, 0, 0, 0);         \
      a2 = __builtin_amdgcn_mfma_f32_16x16x32_f16(WH[5], bh, a2, 0, 0, 0);         \
      a3 = __builtin_amdgcn_mfma_f32_16x16x32_f16(WH[7], bh, a3, 0, 0, 0);         \
      a0 = __builtin_amdgcn_mfma_f32_16x16x32_f16(WL[1], bh, a0, 0, 0, 0);         \
      a1 = __builtin_amdgcn_mfma_f32_16x16x32_f16(WL[3], bh, a1, 0, 0, 0);         \
      a2 = __builtin_amdgcn_mfma_f32_16x16x32_f16(WL[5], bh, a2, 0, 0, 0);         \
      a3 = __builtin_amdgcn_mfma_f32_16x16x32_f16(WL[7], bh, a3, 0, 0, 0);         \
      a0 = __builtin_amdgcn_mfma_f32_16x16x32_f16(WH[1], bl, a0, 0, 0, 0);         \
      a1 = __builtin_amdgcn_mfma_f32_16x16x32_f16(WH[3], bl, a1, 0, 0, 0);         \
      a2 = __builtin_amdgcn_mfma_f32_16x16x32_f16(WH[5], bl, a2, 0, 0, 0);         \
      a3 = __builtin_amdgcn_mfma_f32_16x16x32_f16(WH[7], bl, a3, 0, 0, 0);         \
    }                                                                              \
    float s = 0.f;                                                                 \
    { const f32x4 wv = *(const f32x4*)(lws + kq * 4);                              \
      const f32x4 bv = *(const f32x4*)(lb1 + kq * 4);                              \
      s = fmaf(wv[0], fast_tanh(a0[0] + bv[0]), s);                                \
      s = fmaf(wv[1], fast_tanh(a0[1] + bv[1]), s);                                \
      s = fmaf(wv[2], fast_tanh(a0[2] + bv[2]), s);                                \
      s = fmaf(wv[3], fast_tanh(a0[3] + bv[3]), s); }                              \
    { const f32x4 wv = *(const f32x4*)(lws + 16 + kq * 4);                         \
      const f32x4 bv = *(const f32x4*)(lb1 + 16 + kq * 4);                         \
      s = fmaf(wv[0], fast_tanh(a1[0] + bv[0]), s);                                \
      s = fmaf(wv[1], fast_tanh(a1[1] + bv[1]), s);                                \
      s = fmaf(wv[2], fast_tanh(a1[2] + bv[2]), s);                                \
      s = fmaf(wv[3], fast_tanh(a1[3] + bv[3]), s); }                              \
    { const f32x4 wv = *(const f32x4*)(lws + 32 + kq * 4);                         \
      const f32x4 bv = *(const f32x4*)(lb1 + 32 + kq * 4);                         \
      s = fmaf(wv[0], fast_tanh(a2[0] + bv[0]), s);                                \
      s = fmaf(wv[1], fast_tanh(a2[1] + bv[1]), s);                                \
      s = fmaf(wv[2], fast_tanh(a2[2] + bv[2]), s);                                \
      s = fmaf(wv[3], fast_tanh(a2[3] + bv[3]), s); }                              \
    { const f32x4 wv = *(const f32x4*)(lws + 48 + kq * 4);                         \
      const f32x4 bv = *(const f32x4*)(lb1 + 48 + kq * 4);                         \
      s = fmaf(wv[0], fast_tanh(a3[0] + bv[0]), s);                                \
      s = fmaf(wv[1], fast_tanh(a3[1] + bv[1]), s);                                \
      s = fmaf(wv[2], fast_tanh(a3[2] + bv[2]), s);                                \
      s = fmaf(wv[3], fast_tanh(a3[3] + bv[3]), s); }                              \
    s += __shfl_xor(s, 16);                                                        \
    s += __shfl_xor(s, 32);                                                        \
    if (lane < 16) {                                                               \
      const size_t sr_ = ((size_t)(it_) * GRID_SAL + blockIdx.x) * 64 + wid * 16 + lane; \
      const float z_ = __expf(-fabsf(s));                                          \
      sal[sr_] = fmaxf(s, 0.f) + __logf(1.f + z_);                                 \
    } }

  float4 pA0, pA1, pA2, pA3;
  float4 pB0, pB1, pB2, pB3;

  SAL_LOADS(pA0, pA1, pA2, pA3, 0);
#pragma unroll 1
  for (int it2 = 0; it2 < ITERS; it2 += 2) {
    SAL_LOADS(pB0, pB1, pB2, pB3, it2 + 1);
    SAL_COMPUTE(pA0, pA1, pA2, pA3, it2);
    if (it2 + 2 < ITERS) SAL_LOADS(pA0, pA1, pA2, pA3, it2 + 2);
    SAL_COMPUTE(pB0, pB1, pB2, pB3, it2 + 1);
  }
#undef SAL_LOADS
#undef SAL_COMPUTE
#undef PKSPLIT
}

// ---------- Kernel 2: per-row fused: stats + y_star + hierarchical EXACT top-16 + lift + project ----------
// One 1024-thread block per row. Top-16: wave-local 16 rounds (shfl-only, NO block
// barriers) -> 256 candidates -> wave-0 in-register merge (4/lane, shfl-only).
__global__ __launch_bounds__(1024) void k_rowfinal(
    float* __restrict__ y,               // [B][N]: in = saliency, out = y_star
    const float* __restrict__ x,
    const float* __restrict__ W_lift, const float* __restrict__ b_lift,
    const float* __restrict__ W_proj, const float* __restrict__ b_proj,
    const float* __restrict__ mu, const float* __restrict__ sigma,
    float* __restrict__ tokens) {
  __shared__ float sb[16], ss[16];
  __shared__ float cv[16][16];   // per-wave top-16 values [wave][rank]
  __shared__ int   ci[16][16];   // per-wave top-16 indices
  __shared__ float s_val[MP];
  __shared__ int   s_idx[MP];
  __shared__ float lifted[MP][KD + 1];
  const int b = blockIdx.x, t = threadIdx.x;
  const int wvid = t >> 6, lane = t & 63;
  float* __restrict__ row = y + (size_t)b * N;

  float v[16];
#pragma unroll
  for (int j = 0; j < 16; ++j) v[j] = row[t + 1024 * j];

  // ---- row max ----
  float m = v[0];
#pragma unroll
  for (int j = 1; j < 16; ++j) m = fmaxf(m, v[j]);
#pragma unroll
  for (int off = 1; off < 64; off <<= 1) m = fmaxf(m, __shfl_xor(m, off));
  if (lane == 0) sb[wvid] = m;
  __syncthreads();
  m = sb[0];
#pragma unroll
  for (int w = 1; w < 16; ++w) m = fmaxf(m, sb[w]);

  // ---- softmax denominator ----
  float se = 0.f;
#pragma unroll
  for (int j = 0; j < 16; ++j) se += __expf(v[j] - m);
#pragma unroll
  for (int off = 1; off < 64; off <<= 1) se += __shfl_xor(se, off);
  if (lane == 0) ss[wvid] = se;
  __syncthreads();
  float S = ss[0];
#pragma unroll
  for (int w = 1; w < 16; ++w) S += ss[w];
  const float inv = __builtin_amdgcn_rcpf(S);

  // ---- y_star (before deflation destroys v) ----
#pragma unroll
  for (int j = 0; j < 16; ++j) {
    const float sv = v[j];
    const float sig = __builtin_amdgcn_rcpf(1.f + __expf(-sv));
    row[t + 1024 * j] = fmaf(0.5f, sig, 4.f * __expf(sv - m) * inv);
  }

  // ---- wave-local exact top-16 (value desc, index asc); NO block barriers ----
  for (int k = 0; k < MP; ++k) {
    float bv = v[0]; int bj = 0;
#pragma unroll
    for (int j = 1; j < 16; ++j)
      if (v[j] > bv) { bv = v[j]; bj = j; }      // ascending j => smallest idx kept
    int bi = t + 1024 * bj;
#pragma unroll
    for (int off = 1; off < 64; off <<= 1) {
      const float ov = __shfl_xor(bv, off);
      const int   oi = __shfl_xor(bi, off);
      if (ov > bv || (ov == bv && oi < bi)) { bv = ov; bi = oi; }
    }
    if (lane == 0) { cv[wvid][k] = bv; ci[wvid][k] = bi; }
    // deflate winner (unique owner thread; static indexing)
#pragma unroll
    for (int jj = 0; jj < 16; ++jj)
      if (bi == t + 1024 * jj) v[jj] = -INFINITY;
  }
  __syncthreads();

  // ---- wave 0: merge 256 candidates (4 per lane, in-register, shfl-only) ----
  if (wvid == 0) {
    float mv[4]; int mi[4];
#pragma unroll
    for (int q = 0; q < 4; ++q) {
      const int c = lane + 64 * q;                 // candidate id 0..255
      mv[q] = cv[c >> 4][c & 15];
      mi[q] = ci[c >> 4][c & 15];
    }
    for (int k = 0; k < MP; ++k) {
      float bv = mv[0]; int bi = mi[0];
#pragma unroll
      for (int q = 1; q < 4; ++q)
        if (mv[q] > bv || (mv[q] == bv && mi[q] < bi)) { bv = mv[q]; bi = mi[q]; }
#pragma unroll
      for (int off = 1; off < 64; off <<= 1) {
        const float ov = __shfl_xor(bv, off);
        const int   oi = __shfl_xor(bi, off);
        if (ov > bv || (ov == bv && oi < bi)) { bv = ov; bi = oi; }
      }
      if (lane == 0) { s_val[k] = bv; s_idx[k] = bi; }
      // deflate by unique index
#pragma unroll
      for (int q = 0; q < 4; ++q)
        if (mi[q] == bi) mv[q] = -INFINITY;
    }
  }
  __syncthreads();

  // ---- lift: first 256 threads, (p = t>>4, kd = t&15) ----
  if (t < 256) {
    const int p = t >> 4, kd = t & 15;
    const int idx = s_idx[p];
    const float salv = s_val[p];
    const float* __restrict__ xr = x + ((size_t)b * N + idx) * DIM;
    float a = b_lift[kd];
#pragma unroll 8
    for (int d = 0; d < DIM; ++d)
      a = fmaf((xr[d] - mu[d]) * __builtin_amdgcn_rcpf(sigma[d]), W_lift[d * KD + kd], a);
    a = fmaf((salv - mu[64]) * __builtin_amdgcn_rcpf(sigma[64]), W_lift[64 * KD + kd], a);
    a = fmaf(((float)idx * (1.f / (float)N) - mu[65]) * __builtin_amdgcn_rcpf(sigma[65]),
             W_lift[65 * KD + kd], a);
    lifted[p][kd] = a;
  }
  __syncthreads();

  // ---- project: 1024 threads; (pg = t>>8, d2 = t&255), 4 points each ----
  const int d2 = t & 255, pg = t >> 8;
  const float2* __restrict__ Wp2 = (const float2*)W_proj;
  const float2 bp = ((const float2*)b_proj)[d2];
#pragma unroll
  for (int q = 0; q < 4; ++q) {
    const int p2 = pg * 4 + q;
    float2 o = bp;
#pragma unroll
    for (int c = 0; c < KD; ++c) {
      const float2 w = Wp2[c * 256 + d2];
      o.x = fmaf(lifted[p2][c], w.x, o.x);
      o.y = fmaf(lifted[p2][c], w.y, o.y);
    }
    ((float2*)(tokens + ((size_t)b * MP + p2) * DM))[d2] = o;
  }
}

extern "C" void kernel_launch(void* const* d_in, const int* in_sizes, int n_in,
                              void* d_out, int out_size, void* d_ws, size_t ws_size,
                              hipStream_t stream) {
  const float* x      = (const float*)d_in[0];
  const float* W1     = (const float*)d_in[1];
  const float* b1     = (const float*)d_in[2];
  // d_in[3] = w_e (unused by the reference outputs)
  const float* w_s    = (const float*)d_in[4];
  const float* W_lift = (const float*)d_in[5];
  const float* b_lift = (const float*)d_in[6];
  const float* W_proj = (const float*)d_in[7];
  const float* b_proj = (const float*)d_in[8];
  const float* mu     = (const float*)d_in[9];
  const float* sigma  = (const float*)d_in[10];

  float* tokens = (float*)d_out;                       // [B, MP, DM]
  float* ystar  = (float*)d_out + (size_t)B * MP * DM; // [B, N] (saliency staged here)

  k_saliency<<<GRID_SAL, 256, 0, stream>>>(x, W1, b1, w_s, ystar);
  k_rowfinal<<<B, 1024, 0, stream>>>(ystar, x, W_lift, b_lift,
                                     W_proj, b_proj, mu, sigma, tokens);
}